// Round 1
// baseline (143.683 us; speedup 1.0000x reference)
//
#include <hip/hip_runtime.h>

// SSIM, fused separable implementation.
// img1, img2: (16, 3, 512, 512) fp32. kernel: (3,1,11,11) fp32 (all channels identical,
// separable Gaussian). Output: scalar fp32 mean of ssim_map.

#define IMG_H 512
#define IMG_W 512
#define N_PLANES 48           // 16 * 3
#define KW 11
#define HALO 5
#define TX 32                 // output tile width
#define TY 32                 // output tile height
#define IN_W (TX + 2*HALO)    // 42
#define IN_H (TY + 2*HALO)    // 42
#define TILES_X (IMG_W / TX)  // 16
#define TILES_Y (IMG_H / TY)  // 16
#define TILES_PER_PLANE (TILES_X * TILES_Y)   // 256
#define N_BLOCKS (N_PLANES * TILES_PER_PLANE) // 12288
#define BLOCK 256

#define C1_CONST 1.0e-4f      // 0.01^2
#define C2_CONST 9.0e-4f      // 0.03^2

__global__ __launch_bounds__(BLOCK) void ssim_tile_kernel(
    const float* __restrict__ img1,
    const float* __restrict__ img2,
    const float* __restrict__ kern2d,
    float* __restrict__ partial)
{
    __shared__ float s1[IN_H][IN_W];
    __shared__ float s2[IN_H][IN_W];
    __shared__ float h_m1[IN_H][TX];
    __shared__ float h_m2[IN_H][TX];
    __shared__ float h_x11[IN_H][TX];
    __shared__ float h_x22[IN_H][TX];
    __shared__ float h_x12[IN_H][TX];
    __shared__ float wk[KW];
    __shared__ float wave_sums[BLOCK / 64];

    const int tid = threadIdx.x;

    // Recover normalized 1D kernel: row sums of the normalized 2D kernel.
    if (tid < KW) {
        float s = 0.f;
        #pragma unroll
        for (int j = 0; j < KW; ++j) s += kern2d[tid * KW + j];
        wk[tid] = s;
    }

    // Tile coordinates.
    const int bid   = blockIdx.x;
    const int plane = bid / TILES_PER_PLANE;
    const int trem  = bid % TILES_PER_PLANE;
    const int ty0   = (trem / TILES_X) * TY;
    const int tx0   = (trem % TILES_X) * TX;

    const float* __restrict__ p1 = img1 + (size_t)plane * IMG_H * IMG_W;
    const float* __restrict__ p2 = img2 + (size_t)plane * IMG_H * IMG_W;

    // Stage inputs (with zero halo padding) into LDS.
    for (int i = tid; i < IN_H * IN_W; i += BLOCK) {
        const int r  = i / IN_W;
        const int c  = i - r * IN_W;
        const int gy = ty0 + r - HALO;
        const int gx = tx0 + c - HALO;
        const bool ok = (gy >= 0) & (gy < IMG_H) & (gx >= 0) & (gx < IMG_W);
        float v1 = 0.f, v2 = 0.f;
        if (ok) {
            const int gidx = gy * IMG_W + gx;
            v1 = p1[gidx];
            v2 = p2[gidx];
        }
        s1[r][c] = v1;
        s2[r][c] = v2;
    }
    __syncthreads();

    // Horizontal pass: blur 5 quantities along x for all IN_H rows, TX cols.
    for (int i = tid; i < IN_H * TX; i += BLOCK) {
        const int r = i >> 5;        // / TX
        const int c = i & (TX - 1);  // % TX
        float a1 = 0.f, a2 = 0.f, a11 = 0.f, a22 = 0.f, a12 = 0.f;
        #pragma unroll
        for (int k = 0; k < KW; ++k) {
            const float w  = wk[k];
            const float x1 = s1[r][c + k];
            const float x2 = s2[r][c + k];
            a1  += w * x1;
            a2  += w * x2;
            a11 += w * x1 * x1;
            a22 += w * x2 * x2;
            a12 += w * x1 * x2;
        }
        h_m1[r][c]  = a1;
        h_m2[r][c]  = a2;
        h_x11[r][c] = a11;
        h_x22[r][c] = a22;
        h_x12[r][c] = a12;
    }
    __syncthreads();

    // Vertical pass + SSIM map + partial sum.
    float acc = 0.f;
    for (int i = tid; i < TY * TX; i += BLOCK) {
        const int y = i >> 5;
        const int x = i & (TX - 1);
        float m1 = 0.f, m2 = 0.f, b11 = 0.f, b22 = 0.f, b12 = 0.f;
        #pragma unroll
        for (int k = 0; k < KW; ++k) {
            const float w = wk[k];
            m1  += w * h_m1[y + k][x];
            m2  += w * h_m2[y + k][x];
            b11 += w * h_x11[y + k][x];
            b22 += w * h_x22[y + k][x];
            b12 += w * h_x12[y + k][x];
        }
        const float mu1sq = m1 * m1;
        const float mu2sq = m2 * m2;
        const float mu12  = m1 * m2;
        const float sig1  = b11 - mu1sq;
        const float sig2  = b22 - mu2sq;
        const float sig12 = b12 - mu12;
        const float num = (2.f * mu12 + C1_CONST) * (2.f * sig12 + C2_CONST);
        const float den = (mu1sq + mu2sq + C1_CONST) * (sig1 + sig2 + C2_CONST);
        acc += num / den;
    }

    // Block reduction: wave shuffle, then cross-wave via LDS.
    #pragma unroll
    for (int off = 32; off > 0; off >>= 1)
        acc += __shfl_down(acc, off, 64);
    if ((tid & 63) == 0) wave_sums[tid >> 6] = acc;
    __syncthreads();
    if (tid == 0) {
        float s = 0.f;
        #pragma unroll
        for (int wv = 0; wv < BLOCK / 64; ++wv) s += wave_sums[wv];
        partial[bid] = s;
    }
}

__global__ __launch_bounds__(256) void ssim_reduce_kernel(
    const float* __restrict__ partial, float* __restrict__ out)
{
    const int tid = threadIdx.x;
    double acc = 0.0;
    for (int i = tid; i < N_BLOCKS; i += 256) acc += (double)partial[i];
    #pragma unroll
    for (int off = 32; off > 0; off >>= 1)
        acc += __shfl_down(acc, off, 64);
    __shared__ double wsums[4];
    if ((tid & 63) == 0) wsums[tid >> 6] = acc;
    __syncthreads();
    if (tid == 0) {
        const double total = wsums[0] + wsums[1] + wsums[2] + wsums[3];
        const double inv_n = 1.0 / ((double)N_PLANES * IMG_H * IMG_W);
        out[0] = (float)(total * inv_n);
    }
}

extern "C" void kernel_launch(void* const* d_in, const int* in_sizes, int n_in,
                              void* d_out, int out_size, void* d_ws, size_t ws_size,
                              hipStream_t stream)
{
    const float* img1 = (const float*)d_in[0];
    const float* img2 = (const float*)d_in[1];
    const float* kern = (const float*)d_in[2];
    float* out = (float*)d_out;
    float* partial = (float*)d_ws;   // N_BLOCKS floats = 48 KiB

    ssim_tile_kernel<<<N_BLOCKS, BLOCK, 0, stream>>>(img1, img2, kern, partial);
    ssim_reduce_kernel<<<1, 256, 0, stream>>>(partial, out);
}